// Round 8
// baseline (190.100 us; speedup 1.0000x reference)
//
#include <hip/hip_runtime.h>

#define BATCH 16
#define CH    64
#define LEN   4096
#define NCODE 1024
#define NPTS  (BATCH * LEN)   // 65536
#define LDSP  65              // xs row stride (floats): 65 -> 2 lanes/bank (free)
#define KB    8               // codes per group (x-reuse in regs, dwordx8 w-load)

// ---------------------------------------------------------------------------
// Kernel 1 (prep): cbt[c][k] = cb[k][c]  and  w2[k] = sum_c cb[k][c]^2.
// 16 blocks x 64 codes. Tiny.
// ---------------------------------------------------------------------------
__global__ __launch_bounds__(256) void vq_prep(const float* __restrict__ cb,
                                               float* __restrict__ cbt,
                                               float* __restrict__ w2) {
    __shared__ float tile[64][65];
    const int k0 = blockIdx.x * 64;
    const int t  = threadIdx.x;
#pragma unroll
    for (int r = 0; r < 16; ++r) {
        int idx = r * 256 + t;            // over 64 codes x 64 ch
        int k = idx >> 6, c = idx & 63;
        tile[k][c] = cb[(size_t)(k0 + k) * CH + c];
    }
    __syncthreads();
#pragma unroll
    for (int r = 0; r < 16; ++r) {
        int idx = r * 256 + t;
        int c = idx >> 6, k = idx & 63;   // write coalesced in k
        cbt[(size_t)c * NCODE + k0 + k] = tile[k][c];
    }
    if (t < 64) {
        float s = 0.f;
#pragma unroll
        for (int c = 0; c < CH; ++c) s = fmaf(tile[t][c], tile[t][c], s);
        w2[k0 + t] = s;
    }
}

// ---------------------------------------------------------------------------
// Kernel 2: argmin. Block = 64 points (x in LDS once) x 4 waves (256-code
// slices). Per 8-code group, per channel: 1 ds_read_b32 (x, 2-way bank = free)
// + 1 wave-uniform s_load (8 codebook values at channel c from cbt) + 8
// v_fmac_f32 acc,s,v. LDS traffic 0.25 B/FLOP (round 7's ws-in-LDS was
// 1 B/FLOP = LDS-bound). Only accumulators live across iterations -> nothing
// for RA to remat/spill (rounds 2-6 failure mode).
// ---------------------------------------------------------------------------
__global__ __launch_bounds__(256) void vq_argmin(const float*  __restrict__ x,
                                                 const float*  __restrict__ cbt,
                                                 const float*  __restrict__ w2,
                                                 float*        __restrict__ idx_out,
                                                 double*       __restrict__ partial) {
    __shared__ float  xs[CH * LDSP];
    __shared__ float  sbest[256];
    __shared__ int    skid[256];
    __shared__ double ssum[64];

    const int t    = threadIdx.x;
    const int lane = t & 63;
    const int wave = __builtin_amdgcn_readfirstlane(t >> 6);   // 0..3, scalar
    const int p0   = blockIdx.x * 64;
    const int b    = p0 >> 12;          // / LEN
    const int l0   = p0 & (LEN - 1);

    // ---- stage x tile: xs[c][pt] = x[b][c][l0+pt]   (coalesced reads)
#pragma unroll
    for (int r = 0; r < 16; ++r) {
        int idx = r * 256 + t;          // over 64 ch x 64 pts
        int c = idx >> 6, pt = idx & 63;
        xs[c * LDSP + pt] = x[((size_t)b * CH + c) * LEN + l0 + pt];
    }
    __syncthreads();

    // ---- |x|^2 for my point (same formula as all passing rounds)
    float x2 = 0.f;
#pragma unroll
    for (int c = 0; c < CH; ++c) {
        float v = xs[c * LDSP + lane];
        x2 = fmaf(v, v, x2);
    }

    const float* __restrict__ cbt_s = cbt + wave * (NCODE / 4);  // scalar base
    const float* __restrict__ w2p   = w2 + wave * (NCODE / 4);

    float best  = 3.4e38f;
    int   bestk = 0;

    for (int g = 0; g < (NCODE / 4) / KB; ++g) {   // 32 groups of 8 codes
        float acc[KB];
#pragma unroll
        for (int j = 0; j < KB; ++j) acc[j] = 0.f;

#pragma unroll
        for (int c = 0; c < CH; ++c) {
            float xa = xs[c * LDSP + lane];                     // ds_read_b32
            const float* __restrict__ wr = cbt_s + (size_t)c * NCODE + g * KB;
#pragma unroll
            for (int j = 0; j < KB; ++j)
                acc[j] = fmaf(xa, wr[j], acc[j]);               // v_fmac v,s,v
        }

#pragma unroll
        for (int j = 0; j < KB; ++j) {                           // ascending k
            int   k  = g * KB + j;
            float d2 = (x2 - 2.0f * acc[j]) + w2p[k];
            if (d2 < best) { best = d2; bestk = k; }             // strict <
        }
    }
    bestk += wave * (NCODE / 4);

    sbest[t] = best;
    skid[t]  = bestk;
    __syncthreads();

    if (wave == 0) {
        // merge slices in ascending order (strict < keeps lowest k on ties)
#pragma unroll
        for (int s = 1; s < 4; ++s) {
            float ob = sbest[s * 64 + lane];
            int   ok = skid[s * 64 + lane];
            if (ob < best) { best = ob; bestk = ok; }
        }
        idx_out[p0 + lane] = (float)bestk;
        ssum[lane] = (double)best;      // min d2 == ||x - quant||^2
    }
    __syncthreads();

    if (t == 0) {
        double s = 0.0;
#pragma unroll
        for (int i = 0; i < 64; ++i) s += ssum[i];
        partial[blockIdx.x] = s;
    }
}

// ---------------------------------------------------------------------------
// Kernel 3: quant_out[b,c,l] = codebook[idx[b,l], c]  (coalesced writes)
// ---------------------------------------------------------------------------
__global__ __launch_bounds__(256) void vq_gather(const float* __restrict__ cbk,
                                                 const float* __restrict__ idx_f,
                                                 float*       __restrict__ out) {
    int t  = blockIdx.x * 256 + threadIdx.x;   // over B*C*L
    int l  = t & (LEN - 1);
    int bc = t >> 12;
    int c  = bc & (CH - 1);
    int b  = bc >> 6;
    int k  = (int)idx_f[b * LEN + l];
    out[t] = cbk[(size_t)k * CH + c];
}

// ---------------------------------------------------------------------------
// Kernel 4: final loss reduction over the 1024 per-block partials.
// ---------------------------------------------------------------------------
__global__ __launch_bounds__(256) void vq_loss(const double* __restrict__ partial,
                                               float*        __restrict__ losses) {
    __shared__ double sred[256];
    double v = 0.0;
#pragma unroll
    for (int i = 0; i < 4; ++i) v += partial[threadIdx.x + 256 * i];
    sred[threadIdx.x] = v;
    __syncthreads();
    for (int s = 128; s > 0; s >>= 1) {
        if (threadIdx.x < s) sred[threadIdx.x] += sred[threadIdx.x + s];
        __syncthreads();
    }
    if (threadIdx.x == 0) {
        float loss = (float)(sred[0] / (double)((size_t)NPTS * CH));
        losses[0] = loss;   // codebook_loss
        losses[1] = loss;   // commitment_loss (same value)
    }
}

// ---------------------------------------------------------------------------
extern "C" void kernel_launch(void* const* d_in, const int* in_sizes, int n_in,
                              void* d_out, int out_size, void* d_ws, size_t ws_size,
                              hipStream_t stream) {
    const float* x  = (const float*)d_in[0];   // (B, C, L)
    const float* cb = (const float*)d_in[1];   // (K, C)
    float* out = (float*)d_out;

    // d_out layout: [quant_out (B*C*L)] [codebook_loss] [commitment_loss] [indices (B*L)]
    float* quant_out = out;
    float* losses    = out + (size_t)BATCH * CH * LEN;
    float* idx_out   = losses + 2;

    // ws: [0,8KB) double partials; [8KB,12KB) w2; [16KB,16KB+256KB) cbt
    double* partial = (double*)d_ws;
    float*  w2      = (float*)((char*)d_ws + 8192);
    float*  cbt     = (float*)((char*)d_ws + 16384);

    vq_prep<<<NCODE / 64, 256, 0, stream>>>(cb, cbt, w2);
    vq_argmin<<<NPTS / 64, 256, 0, stream>>>(x, cbt, w2, idx_out, partial);
    vq_gather<<<(BATCH * CH * LEN) / 256, 256, 0, stream>>>(cb, idx_out, quant_out);
    vq_loss<<<1, 256, 0, stream>>>(partial, losses);
}

// Round 9
// 149.765 us; speedup vs baseline: 1.2693x; 1.2693x over previous
//
#include <hip/hip_runtime.h>

#define BATCH 16
#define CH    64
#define LEN   4096
#define NCODE 1024
#define NPTS  (BATCH * LEN)   // 65536
#define MT    128             // points per block
#define NT    64              // codes per n-tile
#define XS_S  132             // xs row stride (floats), 16B-aligned rows
#define WS_S  68              // ws row stride (floats), 16B-aligned rows
#define NPART (NPTS / MT)     // 512 partials

typedef float float4v __attribute__((ext_vector_type(4)));

// ---------------------------------------------------------------------------
// Kernel 1: w2[k] = sum_c codebook[k,c]^2
// ---------------------------------------------------------------------------
__global__ __launch_bounds__(256) void vq_w2(const float* __restrict__ cb,
                                             float* __restrict__ w2) {
    int k = blockIdx.x * 256 + threadIdx.x;
    if (k < NCODE) {
        const float* w = cb + (size_t)k * CH;
        float s = 0.f;
#pragma unroll
        for (int c = 0; c < CH; ++c) s = fmaf(w[c], w[c], s);
        w2[k] = s;
    }
}

// ---------------------------------------------------------------------------
// Kernel 2: LDS-tiled argmin, asymmetric 8x4 register tile.
// Block: 128 points x 64-code n-tiles, 256 thr = 16 pg (8 pts) x 16 cg (4 codes).
// Per k-step per wave: 1 ds_read_b128 (w, 2-way bank = free) + 2 broadcast
// ds_read_b128 (x, 4 distinct addrs) for 2048 MACs -> 0.0107 LDS-cy/MAC
// (round 7's 4x4 was 0.0166 and LDS-instruction-bound at 131us).
// ---------------------------------------------------------------------------
__global__ __launch_bounds__(256, 4) void vq_argmin(const float*  __restrict__ x,
                                                    const float*  __restrict__ cbk,
                                                    const float*  __restrict__ w2,
                                                    float*        __restrict__ idx_out,
                                                    double*       __restrict__ partial) {
    __shared__ __attribute__((aligned(16))) float xs[CH * XS_S];  // xs[ch][pt]
    __shared__ __attribute__((aligned(16))) float ws[CH * WS_S];  // ws[ch][code]
    __shared__ double ssum[16];

    const int t  = threadIdx.x;
    const int cg = t & 15;        // code group: 4 codes
    const int pg = t >> 4;        // point group: 8 points
    const int p0 = blockIdx.x * MT;
    const int b  = p0 >> 12;      // / LEN
    const int l0 = p0 & (LEN - 1);

    // ---- stage x tile: xs[c][l] = x[b][c][l0+l], l in [0,128)  (coalesced f4)
#pragma unroll
    for (int r = 0; r < 8; ++r) {
        int idx = r * 256 + t;        // 2048 float4s total
        int c   = idx >> 5;           // 32 float4 per row
        int l4  = idx & 31;
        *(float4v*)&xs[c * XS_S + 4 * l4] =
            *(const float4v*)&x[((size_t)b * CH + c) * LEN + l0 + 4 * l4];
    }
    __syncthreads();

    // ---- |x|^2 for my 8 points
    float x2[8] = {0.f, 0.f, 0.f, 0.f, 0.f, 0.f, 0.f, 0.f};
#pragma unroll
    for (int k = 0; k < CH; ++k) {
        float4v a0 = *(const float4v*)&xs[k * XS_S + 8 * pg];
        float4v a1 = *(const float4v*)&xs[k * XS_S + 8 * pg + 4];
        x2[0] = fmaf(a0.x, a0.x, x2[0]);
        x2[1] = fmaf(a0.y, a0.y, x2[1]);
        x2[2] = fmaf(a0.z, a0.z, x2[2]);
        x2[3] = fmaf(a0.w, a0.w, x2[3]);
        x2[4] = fmaf(a1.x, a1.x, x2[4]);
        x2[5] = fmaf(a1.y, a1.y, x2[5]);
        x2[6] = fmaf(a1.z, a1.z, x2[6]);
        x2[7] = fmaf(a1.w, a1.w, x2[7]);
    }

    float best[8];
    int   bestk[8];
#pragma unroll
    for (int i = 0; i < 8; ++i) { best[i] = 3.4e38f; bestk[i] = 0; }

    for (int nt = 0; nt < NCODE / NT; ++nt) {
        __syncthreads();   // previous tile's ws reads complete
        // ---- stage w tile (transposed): ws[c][n] = cbk[nt*NT+n][c]
        {
            const int code = t & 63, cq = t >> 6;
            const float* src = cbk + ((size_t)(nt * NT + code)) * CH + cq * 16;
#pragma unroll
            for (int j = 0; j < 4; ++j) {
                float4v v = *(const float4v*)(src + 4 * j);
                ws[(cq * 16 + 4 * j + 0) * WS_S + code] = v.x;
                ws[(cq * 16 + 4 * j + 1) * WS_S + code] = v.y;
                ws[(cq * 16 + 4 * j + 2) * WS_S + code] = v.z;
                ws[(cq * 16 + 4 * j + 3) * WS_S + code] = v.w;
            }
        }
        __syncthreads();

        // ---- 8x4 dot-product patch
        float acc[8][4] = {{0.f}};
#pragma unroll 8
        for (int k = 0; k < CH; ++k) {
            float4v wb = *(const float4v*)&ws[k * WS_S + 4 * cg];
            float4v a0 = *(const float4v*)&xs[k * XS_S + 8 * pg];
            float4v a1 = *(const float4v*)&xs[k * XS_S + 8 * pg + 4];
            acc[0][0] = fmaf(a0.x, wb.x, acc[0][0]);
            acc[0][1] = fmaf(a0.x, wb.y, acc[0][1]);
            acc[0][2] = fmaf(a0.x, wb.z, acc[0][2]);
            acc[0][3] = fmaf(a0.x, wb.w, acc[0][3]);
            acc[1][0] = fmaf(a0.y, wb.x, acc[1][0]);
            acc[1][1] = fmaf(a0.y, wb.y, acc[1][1]);
            acc[1][2] = fmaf(a0.y, wb.z, acc[1][2]);
            acc[1][3] = fmaf(a0.y, wb.w, acc[1][3]);
            acc[2][0] = fmaf(a0.z, wb.x, acc[2][0]);
            acc[2][1] = fmaf(a0.z, wb.y, acc[2][1]);
            acc[2][2] = fmaf(a0.z, wb.z, acc[2][2]);
            acc[2][3] = fmaf(a0.z, wb.w, acc[2][3]);
            acc[3][0] = fmaf(a0.w, wb.x, acc[3][0]);
            acc[3][1] = fmaf(a0.w, wb.y, acc[3][1]);
            acc[3][2] = fmaf(a0.w, wb.z, acc[3][2]);
            acc[3][3] = fmaf(a0.w, wb.w, acc[3][3]);
            acc[4][0] = fmaf(a1.x, wb.x, acc[4][0]);
            acc[4][1] = fmaf(a1.x, wb.y, acc[4][1]);
            acc[4][2] = fmaf(a1.x, wb.z, acc[4][2]);
            acc[4][3] = fmaf(a1.x, wb.w, acc[4][3]);
            acc[5][0] = fmaf(a1.y, wb.x, acc[5][0]);
            acc[5][1] = fmaf(a1.y, wb.y, acc[5][1]);
            acc[5][2] = fmaf(a1.y, wb.z, acc[5][2]);
            acc[5][3] = fmaf(a1.y, wb.w, acc[5][3]);
            acc[6][0] = fmaf(a1.z, wb.x, acc[6][0]);
            acc[6][1] = fmaf(a1.z, wb.y, acc[6][1]);
            acc[6][2] = fmaf(a1.z, wb.z, acc[6][2]);
            acc[6][3] = fmaf(a1.z, wb.w, acc[6][3]);
            acc[7][0] = fmaf(a1.w, wb.x, acc[7][0]);
            acc[7][1] = fmaf(a1.w, wb.y, acc[7][1]);
            acc[7][2] = fmaf(a1.w, wb.z, acc[7][2]);
            acc[7][3] = fmaf(a1.w, wb.w, acc[7][3]);
        }

        // ---- argmin update (this thread's codes, ascending k, strict <)
#pragma unroll
        for (int j = 0; j < 4; ++j) {
            int   k   = nt * NT + 4 * cg + j;
            float w2k = w2[k];
#pragma unroll
            for (int i = 0; i < 8; ++i) {
                float d2 = (x2[i] - 2.0f * acc[i][j]) + w2k;
                if (d2 < best[i]) { best[i] = d2; bestk[i] = k; }
            }
        }
    }

    // ---- butterfly across the 16 cg lanes (lane bits 0..3); smaller-k ties
#pragma unroll
    for (int m = 1; m < 16; m <<= 1) {
#pragma unroll
        for (int i = 0; i < 8; ++i) {
            float ob = __shfl_xor(best[i], m, 64);
            int   ok = __shfl_xor(bestk[i], m, 64);
            if (ob < best[i] || (ob == best[i] && ok < bestk[i])) {
                best[i] = ob; bestk[i] = ok;
            }
        }
    }

    if (cg == 0) {
        double s = 0.0;
#pragma unroll
        for (int i = 0; i < 8; ++i) {
            idx_out[p0 + 8 * pg + i] = (float)bestk[i];
            s += (double)best[i];          // min d2 == ||x - quant||^2
        }
        ssum[pg] = s;
    }
    __syncthreads();

    if (t == 0) {
        double s = 0.0;
#pragma unroll
        for (int i = 0; i < 16; ++i) s += ssum[i];
        partial[blockIdx.x] = s;
    }
}

// ---------------------------------------------------------------------------
// Kernel 3: quant_out[b,c,l] = codebook[idx[b,l], c]  (coalesced writes)
// ---------------------------------------------------------------------------
__global__ __launch_bounds__(256) void vq_gather(const float* __restrict__ cbk,
                                                 const float* __restrict__ idx_f,
                                                 float*       __restrict__ out) {
    int t  = blockIdx.x * 256 + threadIdx.x;   // over B*C*L
    int l  = t & (LEN - 1);
    int bc = t >> 12;
    int c  = bc & (CH - 1);
    int b  = bc >> 6;
    int k  = (int)idx_f[b * LEN + l];
    out[t] = cbk[(size_t)k * CH + c];
}

// ---------------------------------------------------------------------------
// Kernel 4: final loss reduction over the NPART per-block partials.
// ---------------------------------------------------------------------------
__global__ __launch_bounds__(256) void vq_loss(const double* __restrict__ partial,
                                               float*        __restrict__ losses) {
    __shared__ double sred[256];
    double v = 0.0;
#pragma unroll
    for (int i = 0; i < NPART / 256; ++i) v += partial[threadIdx.x + 256 * i];
    sred[threadIdx.x] = v;
    __syncthreads();
    for (int s = 128; s > 0; s >>= 1) {
        if (threadIdx.x < s) sred[threadIdx.x] += sred[threadIdx.x + s];
        __syncthreads();
    }
    if (threadIdx.x == 0) {
        float loss = (float)(sred[0] / (double)((size_t)NPTS * CH));
        losses[0] = loss;   // codebook_loss
        losses[1] = loss;   // commitment_loss (same value)
    }
}

// ---------------------------------------------------------------------------
extern "C" void kernel_launch(void* const* d_in, const int* in_sizes, int n_in,
                              void* d_out, int out_size, void* d_ws, size_t ws_size,
                              hipStream_t stream) {
    const float* x  = (const float*)d_in[0];   // (B, C, L)
    const float* cb = (const float*)d_in[1];   // (K, C)
    float* out = (float*)d_out;

    // d_out layout: [quant_out (B*C*L)] [codebook_loss] [commitment_loss] [indices (B*L)]
    float* quant_out = out;
    float* losses    = out + (size_t)BATCH * CH * LEN;
    float* idx_out   = losses + 2;

    // workspace: [0, 8KB): double partials (NPART); [8KB, 12KB): w2 (1024 floats)
    double* partial = (double*)d_ws;
    float*  w2      = (float*)((char*)d_ws + 8192);

    vq_w2<<<NCODE / 256, 256, 0, stream>>>(cb, w2);
    vq_argmin<<<NPTS / MT, 256, 0, stream>>>(x, cb, w2, idx_out, partial);
    vq_gather<<<(BATCH * CH * LEN) / 256, 256, 0, stream>>>(cb, idx_out, quant_out);
    vq_loss<<<1, 256, 0, stream>>>(partial, losses);
}

// Round 10
// 149.721 us; speedup vs baseline: 1.2697x; 1.0003x over previous
//
#include <hip/hip_runtime.h>

#define BATCH 16
#define CH    64
#define LEN   4096
#define NCODE 1024
#define NPTS  (BATCH * LEN)   // 65536
#define MT    128             // points per block
#define NT    64              // codes per n-tile
#define XS_S  132             // xs row stride (floats), 16B-aligned rows
#define WS_S  68              // ws row stride (floats), 16B-aligned rows
#define NPART (NPTS / MT)     // 512 partials

typedef float float4v __attribute__((ext_vector_type(4)));

// ---------------------------------------------------------------------------
// Kernel 1: w2[k] = sum_c codebook[k,c]^2
// ---------------------------------------------------------------------------
__global__ __launch_bounds__(256) void vq_w2(const float* __restrict__ cb,
                                             float* __restrict__ w2) {
    int k = blockIdx.x * 256 + threadIdx.x;
    if (k < NCODE) {
        const float* w = cb + (size_t)k * CH;
        float s = 0.f;
#pragma unroll
        for (int c = 0; c < CH; ++c) s = fmaf(w[c], w[c], s);
        w2[k] = s;
    }
}

// ---------------------------------------------------------------------------
// Kernel 2: LDS-tiled argmin, asymmetric 8x4 register tile.
// Block: 128 points x 64-code n-tiles, 256 thr = 16 pg (8 pts) x 16 cg (4 codes).
// Per k-step per wave: 1 ds_read_b128 (w, 2-way bank = free) + 2 broadcast
// ds_read_b128 (x, 4 distinct addrs) for 2048 MACs -> 0.0107 LDS-cy/MAC
// (round 7's 4x4 was 0.0166 and LDS-instruction-bound at 131us).
// ---------------------------------------------------------------------------
__global__ __launch_bounds__(256, 4) void vq_argmin(const float*  __restrict__ x,
                                                    const float*  __restrict__ cbk,
                                                    const float*  __restrict__ w2,
                                                    float*        __restrict__ idx_out,
                                                    double*       __restrict__ partial) {
    __shared__ __attribute__((aligned(16))) float xs[CH * XS_S];  // xs[ch][pt]
    __shared__ __attribute__((aligned(16))) float ws[CH * WS_S];  // ws[ch][code]
    __shared__ double ssum[16];

    const int t  = threadIdx.x;
    const int cg = t & 15;        // code group: 4 codes
    const int pg = t >> 4;        // point group: 8 points
    const int p0 = blockIdx.x * MT;
    const int b  = p0 >> 12;      // / LEN
    const int l0 = p0 & (LEN - 1);

    // ---- stage x tile: xs[c][l] = x[b][c][l0+l], l in [0,128)  (coalesced f4)
#pragma unroll
    for (int r = 0; r < 8; ++r) {
        int idx = r * 256 + t;        // 2048 float4s total
        int c   = idx >> 5;           // 32 float4 per row
        int l4  = idx & 31;
        *(float4v*)&xs[c * XS_S + 4 * l4] =
            *(const float4v*)&x[((size_t)b * CH + c) * LEN + l0 + 4 * l4];
    }
    __syncthreads();

    // ---- |x|^2 for my 8 points
    float x2[8] = {0.f, 0.f, 0.f, 0.f, 0.f, 0.f, 0.f, 0.f};
#pragma unroll
    for (int k = 0; k < CH; ++k) {
        float4v a0 = *(const float4v*)&xs[k * XS_S + 8 * pg];
        float4v a1 = *(const float4v*)&xs[k * XS_S + 8 * pg + 4];
        x2[0] = fmaf(a0.x, a0.x, x2[0]);
        x2[1] = fmaf(a0.y, a0.y, x2[1]);
        x2[2] = fmaf(a0.z, a0.z, x2[2]);
        x2[3] = fmaf(a0.w, a0.w, x2[3]);
        x2[4] = fmaf(a1.x, a1.x, x2[4]);
        x2[5] = fmaf(a1.y, a1.y, x2[5]);
        x2[6] = fmaf(a1.z, a1.z, x2[6]);
        x2[7] = fmaf(a1.w, a1.w, x2[7]);
    }

    float best[8];
    int   bestk[8];
#pragma unroll
    for (int i = 0; i < 8; ++i) { best[i] = 3.4e38f; bestk[i] = 0; }

    for (int nt = 0; nt < NCODE / NT; ++nt) {
        __syncthreads();   // previous tile's ws reads complete
        // ---- stage w tile (transposed): ws[c][n] = cbk[nt*NT+n][c]
        {
            const int code = t & 63, cq = t >> 6;
            const float* src = cbk + ((size_t)(nt * NT + code)) * CH + cq * 16;
#pragma unroll
            for (int j = 0; j < 4; ++j) {
                float4v v = *(const float4v*)(src + 4 * j);
                ws[(cq * 16 + 4 * j + 0) * WS_S + code] = v.x;
                ws[(cq * 16 + 4 * j + 1) * WS_S + code] = v.y;
                ws[(cq * 16 + 4 * j + 2) * WS_S + code] = v.z;
                ws[(cq * 16 + 4 * j + 3) * WS_S + code] = v.w;
            }
        }
        __syncthreads();

        // ---- 8x4 dot-product patch
        float acc[8][4] = {{0.f}};
#pragma unroll 8
        for (int k = 0; k < CH; ++k) {
            float4v wb = *(const float4v*)&ws[k * WS_S + 4 * cg];
            float4v a0 = *(const float4v*)&xs[k * XS_S + 8 * pg];
            float4v a1 = *(const float4v*)&xs[k * XS_S + 8 * pg + 4];
            acc[0][0] = fmaf(a0.x, wb.x, acc[0][0]);
            acc[0][1] = fmaf(a0.x, wb.y, acc[0][1]);
            acc[0][2] = fmaf(a0.x, wb.z, acc[0][2]);
            acc[0][3] = fmaf(a0.x, wb.w, acc[0][3]);
            acc[1][0] = fmaf(a0.y, wb.x, acc[1][0]);
            acc[1][1] = fmaf(a0.y, wb.y, acc[1][1]);
            acc[1][2] = fmaf(a0.y, wb.z, acc[1][2]);
            acc[1][3] = fmaf(a0.y, wb.w, acc[1][3]);
            acc[2][0] = fmaf(a0.z, wb.x, acc[2][0]);
            acc[2][1] = fmaf(a0.z, wb.y, acc[2][1]);
            acc[2][2] = fmaf(a0.z, wb.z, acc[2][2]);
            acc[2][3] = fmaf(a0.z, wb.w, acc[2][3]);
            acc[3][0] = fmaf(a0.w, wb.x, acc[3][0]);
            acc[3][1] = fmaf(a0.w, wb.y, acc[3][1]);
            acc[3][2] = fmaf(a0.w, wb.z, acc[3][2]);
            acc[3][3] = fmaf(a0.w, wb.w, acc[3][3]);
            acc[4][0] = fmaf(a1.x, wb.x, acc[4][0]);
            acc[4][1] = fmaf(a1.x, wb.y, acc[4][1]);
            acc[4][2] = fmaf(a1.x, wb.z, acc[4][2]);
            acc[4][3] = fmaf(a1.x, wb.w, acc[4][3]);
            acc[5][0] = fmaf(a1.y, wb.x, acc[5][0]);
            acc[5][1] = fmaf(a1.y, wb.y, acc[5][1]);
            acc[5][2] = fmaf(a1.y, wb.z, acc[5][2]);
            acc[5][3] = fmaf(a1.y, wb.w, acc[5][3]);
            acc[6][0] = fmaf(a1.z, wb.x, acc[6][0]);
            acc[6][1] = fmaf(a1.z, wb.y, acc[6][1]);
            acc[6][2] = fmaf(a1.z, wb.z, acc[6][2]);
            acc[6][3] = fmaf(a1.z, wb.w, acc[6][3]);
            acc[7][0] = fmaf(a1.w, wb.x, acc[7][0]);
            acc[7][1] = fmaf(a1.w, wb.y, acc[7][1]);
            acc[7][2] = fmaf(a1.w, wb.z, acc[7][2]);
            acc[7][3] = fmaf(a1.w, wb.w, acc[7][3]);
        }

        // ---- argmin update (this thread's codes, ascending k, strict <)
#pragma unroll
        for (int j = 0; j < 4; ++j) {
            int   k   = nt * NT + 4 * cg + j;
            float w2k = w2[k];
#pragma unroll
            for (int i = 0; i < 8; ++i) {
                float d2 = (x2[i] - 2.0f * acc[i][j]) + w2k;
                if (d2 < best[i]) { best[i] = d2; bestk[i] = k; }
            }
        }
    }

    // ---- butterfly across the 16 cg lanes (lane bits 0..3); smaller-k ties
#pragma unroll
    for (int m = 1; m < 16; m <<= 1) {
#pragma unroll
        for (int i = 0; i < 8; ++i) {
            float ob = __shfl_xor(best[i], m, 64);
            int   ok = __shfl_xor(bestk[i], m, 64);
            if (ob < best[i] || (ob == best[i] && ok < bestk[i])) {
                best[i] = ob; bestk[i] = ok;
            }
        }
    }

    if (cg == 0) {
        double s = 0.0;
#pragma unroll
        for (int i = 0; i < 8; ++i) {
            idx_out[p0 + 8 * pg + i] = (float)bestk[i];
            s += (double)best[i];          // min d2 == ||x - quant||^2
        }
        ssum[pg] = s;
    }
    __syncthreads();

    if (t == 0) {
        double s = 0.0;
#pragma unroll
        for (int i = 0; i < 16; ++i) s += ssum[i];
        partial[blockIdx.x] = s;
    }
}

// ---------------------------------------------------------------------------
// Kernel 3: quant_out[b,c,l] = codebook[idx[b,l], c]  (coalesced writes)
// ---------------------------------------------------------------------------
__global__ __launch_bounds__(256) void vq_gather(const float* __restrict__ cbk,
                                                 const float* __restrict__ idx_f,
                                                 float*       __restrict__ out) {
    int t  = blockIdx.x * 256 + threadIdx.x;   // over B*C*L
    int l  = t & (LEN - 1);
    int bc = t >> 12;
    int c  = bc & (CH - 1);
    int b  = bc >> 6;
    int k  = (int)idx_f[b * LEN + l];
    out[t] = cbk[(size_t)k * CH + c];
}

// ---------------------------------------------------------------------------
// Kernel 4: final loss reduction over the NPART per-block partials.
// ---------------------------------------------------------------------------
__global__ __launch_bounds__(256) void vq_loss(const double* __restrict__ partial,
                                               float*        __restrict__ losses) {
    __shared__ double sred[256];
    double v = 0.0;
#pragma unroll
    for (int i = 0; i < NPART / 256; ++i) v += partial[threadIdx.x + 256 * i];
    sred[threadIdx.x] = v;
    __syncthreads();
    for (int s = 128; s > 0; s >>= 1) {
        if (threadIdx.x < s) sred[threadIdx.x] += sred[threadIdx.x + s];
        __syncthreads();
    }
    if (threadIdx.x == 0) {
        float loss = (float)(sred[0] / (double)((size_t)NPTS * CH));
        losses[0] = loss;   // codebook_loss
        losses[1] = loss;   // commitment_loss (same value)
    }
}

// ---------------------------------------------------------------------------
extern "C" void kernel_launch(void* const* d_in, const int* in_sizes, int n_in,
                              void* d_out, int out_size, void* d_ws, size_t ws_size,
                              hipStream_t stream) {
    const float* x  = (const float*)d_in[0];   // (B, C, L)
    const float* cb = (const float*)d_in[1];   // (K, C)
    float* out = (float*)d_out;

    // d_out layout: [quant_out (B*C*L)] [codebook_loss] [commitment_loss] [indices (B*L)]
    float* quant_out = out;
    float* losses    = out + (size_t)BATCH * CH * LEN;
    float* idx_out   = losses + 2;

    // workspace: [0, 8KB): double partials (NPART); [8KB, 12KB): w2 (1024 floats)
    double* partial = (double*)d_ws;
    float*  w2      = (float*)((char*)d_ws + 8192);

    vq_w2<<<NCODE / 256, 256, 0, stream>>>(cb, w2);
    vq_argmin<<<NPTS / MT, 256, 0, stream>>>(x, cb, w2, idx_out, partial);
    vq_gather<<<(BATCH * CH * LEN) / 256, 256, 0, stream>>>(cb, idx_out, quant_out);
    vq_loss<<<1, 256, 0, stream>>>(partial, losses);
}